// Round 7
// baseline (76.080 us; speedup 1.0000x reference)
//
#include <hip/hip_runtime.h>
#include <math.h>

#define S_LEN  2048
#define D_HEAD 128
#define QBLK   64
#define KVBLK  64
#define NWAVES 4
#define BATCH  16
#define NKVT   (S_LEN / KVBLK)     // 32 kv tiles per batch
#define TILE_SH 8192               // shorts per 64x128 tile image (16 KB)
#define CH_PB  80                  // chunks per batch (qb desc, balanced <=8-tile)
#define PCH_PB 72                  // partial chunks per batch (o < 72)

typedef __attribute__((ext_vector_type(4))) float f32x4;
typedef __attribute__((ext_vector_type(8))) short short8;

__device__ __forceinline__ unsigned short f2bf(float x) {
    union { float f; unsigned u; } v; v.f = x;
    unsigned r = v.u + 0x7fffu + ((v.u >> 16) & 1u);
    return (unsigned short)(r >> 16);
}
__device__ __forceinline__ float bf2f(unsigned short h) {
    union { unsigned u; float f; } v; v.u = ((unsigned)h) << 16;
    return v.f;
}
__device__ __forceinline__ unsigned pack2(unsigned short a, unsigned short b) {
    return (unsigned)a | ((unsigned)b << 16);
}
__device__ __forceinline__ unsigned cvtpk(float lo, float hi) {
    unsigned r;
    asm("v_cvt_pk_bf16_f32 %0, %1, %2" : "=v"(r) : "v"(lo), "v"(hi));
    return r;
}
__device__ __forceinline__ void gld16(const void* g, void* l) {
    __builtin_amdgcn_global_load_lds(
        (const __attribute__((address_space(1))) void*)g,
        (__attribute__((address_space(3))) void*)l, 16, 0, 0);
}
template<int N> __device__ __forceinline__ void wait_vm() {
    asm volatile("s_waitcnt vmcnt(%0)" :: "i"(N) : "memory");
}
__device__ __forceinline__ void barrier() {
    __builtin_amdgcn_sched_barrier(0);
    __builtin_amdgcn_s_barrier();
    __builtin_amdgcn_sched_barrier(0);
}

// prep: one block per (batch, kv-tile). Emits PRE-SWIZZLED contiguous LDS images.
__global__ __launch_bounds__(256) void prep(const float* __restrict__ K,
                                            const float* __restrict__ V,
                                            unsigned short* __restrict__ Kp,
                                            unsigned short* __restrict__ Vp)
{
    const int tid = threadIdx.x;
    const int bid = blockIdx.x;
    const int b = bid >> 5, t = bid & 31;
    const size_t ibase = (size_t)b * S_LEN * D_HEAD + (size_t)t * KVBLK * D_HEAD;
    unsigned short* ko = Kp + (size_t)bid * TILE_SH;
    unsigned short* vo = Vp + (size_t)bid * TILE_SH;

    #pragma unroll
    for (int c = 0; c < 4; ++c) {
        int i  = c * 256 + tid;
        int k  = i >> 4;
        int d8 = ((i & 15) * 8) ^ ((k & 7) << 3);
        const float* sp = K + ibase + (size_t)k * D_HEAD + d8;
        float4 a = *(const float4*)sp;
        float4 bb = *(const float4*)(sp + 4);
        uint4 u = { pack2(f2bf(a.x),f2bf(a.y)),  pack2(f2bf(a.z),f2bf(a.w)),
                    pack2(f2bf(bb.x),f2bf(bb.y)),pack2(f2bf(bb.z),f2bf(bb.w)) };
        *(uint4*)(ko + i * 8) = u;
    }

    __shared__ unsigned short Vb[KVBLK][D_HEAD + 2];
    {
        const int r  = tid >> 2;
        const int c0 = (tid & 3) * 32;
        const float* sp = V + ibase + (size_t)r * D_HEAD + c0;
        #pragma unroll
        for (int i = 0; i < 8; ++i) {
            float4 x = *(const float4*)(sp + i * 4);
            Vb[r][c0+i*4+0] = f2bf(x.x); Vb[r][c0+i*4+1] = f2bf(x.y);
            Vb[r][c0+i*4+2] = f2bf(x.z); Vb[r][c0+i*4+3] = f2bf(x.w);
        }
    }
    __syncthreads();
    #pragma unroll
    for (int c = 0; c < 4; ++c) {
        int i   = c * 256 + tid;
        int d   = i >> 3;
        int kk0 = ((i & 7) * 8) ^ ((d & 7) << 3);
        unsigned short h[8];
        #pragma unroll
        for (int j = 0; j < 8; ++j) h[j] = Vb[kk0 + j][d];
        uint4 u = { pack2(h[0],h[1]), pack2(h[2],h[3]), pack2(h[4],h[5]), pack2(h[6],h[7]) };
        *(uint4*)(vo + i * 8) = u;
    }
}

// MODE 1: 1280 uniform chunks (<=8 tiles). bid = o*16 + b; XCD = b%8 (2 batches/XCD).
//   o<72: partial chunk of heavy q-block (bf16 Po + m,l).  o>=72: qb 0..7, direct.
// MODE 0 (fallback): 512 blocks, complementary pairing, all direct.
template<int MODE>
__global__ __launch_bounds__(256, 2)
void attn_fwd(const float* __restrict__ Qg, const unsigned short* __restrict__ Kp,
              const unsigned short* __restrict__ Vp, float* __restrict__ Og,
              unsigned short* __restrict__ Po, float* __restrict__ Ml)
{
    constexpr float CSC = 0.12751744f;      // log2(e)/sqrt(128), folded into Q
    const int tid  = threadIdx.x;
    const int lane = tid & 63;
    const int w    = tid >> 6;
    const int bid  = blockIdx.x;

    int b, qb, lo_t, hi_t, pslot = -1;
    if (MODE == 0) {
        b = bid & 15;
        const int rank = bid >> 4;
        qb = (rank < 16) ? (31 - rank) : (rank - 16);
        lo_t = 0; hi_t = qb + 1;
    } else {
        const int o = bid >> 4;             // 0..79, sorted by chunk size desc
        b = bid & 15;                       // XCD = b % 8
        int ci, C;
        if (o < 32)      { qb = 31 - (o >> 2); ci = o & 3;  C = 4; }
        else if (o < 56) { int t = o - 32; qb = 23 - t / 3; ci = t % 3; C = 3; }
        else if (o < 72) { int t = o - 56; qb = 15 - (t >> 1); ci = t & 1; C = 2; }
        else             { qb = 7 - (o - 72); ci = 0; C = 1; }
        const int n = qb + 1;
        const int bsz = n / C, rem = n % C;
        lo_t = ci * bsz + min(ci, rem);
        hi_t = lo_t + bsz + (ci < rem ? 1 : 0);
        pslot = (C > 1) ? b * PCH_PB + o : -1;
    }
    const int q0   = qb * QBLK;
    const int q0w  = q0 + w * 16;
    const int qc   = lane & 15;
    const int g    = lane >> 4;

    __shared__ __align__(16) unsigned short Klds[2][TILE_SH];         // 32 KB
    __shared__ __align__(16) unsigned short Vlds[2][TILE_SH];         // 32 KB
    __shared__ __align__(16) unsigned short Plds[NWAVES][16 * KVBLK]; //  8 KB

    const size_t base = (size_t)b * S_LEN * D_HEAD;
    const int tb = b * NKVT;

    auto stage = [&](int t) {               // 8 DMA issues/wave -> buffer t&1
        const int dst = t & 1;
        const unsigned short* ks = Kp + (size_t)(tb + t) * TILE_SH + w * 2048 + lane * 8;
        const unsigned short* vs = Vp + (size_t)(tb + t) * TILE_SH + w * 2048 + lane * 8;
        #pragma unroll
        for (int ii = 0; ii < 4; ++ii) {
            gld16(ks + ii * 512, &Klds[dst][w * 2048 + ii * 512]);
            gld16(vs + ii * 512, &Vlds[dst][w * 2048 + ii * 512]);
        }
    };

    stage(lo_t);                            // DMA underway while Q loads

    // ---- Q fragments (MFMA B operand), pre-scaled ----
    short8 qf[4];
    {
        const float* qp = Qg + base + (size_t)(q0w + qc) * D_HEAD + g * 8;
        #pragma unroll
        for (int db = 0; db < 4; ++db) {
            float4 x0 = *(const float4*)(qp + db * 32);
            float4 x1 = *(const float4*)(qp + db * 32 + 4);
            float tt[8] = {x0.x, x0.y, x0.z, x0.w, x1.x, x1.y, x1.z, x1.w};
            short8 f;
            #pragma unroll
            for (int j = 0; j < 8; ++j) f[j] = (short)f2bf(tt[j] * CSC);
            qf[db] = f;
        }
    }

    f32x4 o[8] = {};                        // o[db][r] = O[q=4g+r][d=db*16+qc]
    float m = -1e30f, lsum = 0.f;           // lsum lane-partial until epilogue
    const int qidx = q0w + qc;
    const int nt = hi_t - lo_t;

    for (int i = 0; i < nt; ++i) {
        const int t   = lo_t + i;
        const int buf = t & 1;
        const int kv0 = t * KVBLK;
        const bool more = (i + 1 < nt);

        if (more) { stage(t + 1); wait_vm<8>(); }   // tile t landed; t+1 in flight
        else      { wait_vm<0>(); }
        barrier();

        const int t16max = min(3, (q0w + 15 - kv0) >> 4);
        const int ksmax  = min(1, (q0w + 15 - kv0) >> 5);

        // ---- swapped QK^T: rows = k, cols = q ----
        f32x4 st[4] = {};
        __builtin_amdgcn_s_setprio(1);
        #pragma unroll
        for (int t16 = 0; t16 < 4; ++t16) {
            if (t16 <= t16max) {
                const int kr = t16 * 16 + qc;
                const int swz = (kr & 7) << 3;
                #pragma unroll
                for (int db = 0; db < 4; ++db) {
                    short8 kf = *(const short8*)&Klds[buf][(kr * 128 + db * 32 + g * 8) ^ swz];
                    st[t16] = __builtin_amdgcn_mfma_f32_16x16x32_bf16(kf, qf[db], st[t16], 0, 0, 0);
                }
            }
        }
        __builtin_amdgcn_s_setprio(0);

        float s[16];
        #pragma unroll
        for (int t16 = 0; t16 < 4; ++t16)
            #pragma unroll
            for (int r = 0; r < 4; ++r)
                s[t16*4+r] = (t16 <= t16max) ? st[t16][r] : -1e30f;

        if (kv0 + KVBLK - 1 > q0w) {        // diagonal: per-lane causal mask
            #pragma unroll
            for (int t16 = 0; t16 < 4; ++t16)
                #pragma unroll
                for (int r = 0; r < 4; ++r)
                    if (kv0 + t16 * 16 + g * 4 + r > qidx) s[t16*4+r] = -1e30f;
        }

        // ---- online softmax, defer-max; no cross-lane ops in common path ----
        float m0 = fmaxf(fmaxf(s[0],s[1]), fmaxf(s[2],s[3]));
        float m1 = fmaxf(fmaxf(s[4],s[5]), fmaxf(s[6],s[7]));
        float m2 = fmaxf(fmaxf(s[8],s[9]), fmaxf(s[10],s[11]));
        float m3 = fmaxf(fmaxf(s[12],s[13]), fmaxf(s[14],s[15]));
        float mx = fmaxf(fmaxf(m0,m1), fmaxf(m2,m3));

        if (__any(mx > m + 8.0f)) {
            mx = fmaxf(mx, __shfl_xor(mx, 16));
            mx = fmaxf(mx, __shfl_xor(mx, 32));
            float mnew = fmaxf(m, mx);
            float alpha = exp2f(m - mnew);
            m = mnew;
            lsum *= alpha;
            float a_o[4];
            #pragma unroll
            for (int r = 0; r < 4; ++r) a_o[r] = __shfl(alpha, g * 4 + r);
            #pragma unroll
            for (int db = 0; db < 8; ++db)
                #pragma unroll
                for (int r = 0; r < 4; ++r) o[db][r] *= a_o[r];
        }

        float p[16];
        #pragma unroll
        for (int ii = 0; ii < 16; ++ii) p[ii] = exp2f(s[ii] - m);
        float r0 = (p[0]+p[1]) + (p[2]+p[3]);
        float r1 = (p[4]+p[5]) + (p[6]+p[7]);
        float r2 = (p[8]+p[9]) + (p[10]+p[11]);
        float r3 = (p[12]+p[13]) + (p[14]+p[15]);
        lsum += (r0+r1) + (r2+r3);

        // ---- P -> wave-private LDS (bf16, swizzled) ----
        const int pswz = (qc & 7) << 3;
        #pragma unroll
        for (int t16 = 0; t16 < 4; ++t16) {
            uint2 u = { cvtpk(p[t16*4+0], p[t16*4+1]), cvtpk(p[t16*4+2], p[t16*4+3]) };
            *(uint2*)&Plds[w][(qc * 64 + t16 * 16 + g * 4) ^ pswz] = u;
        }

        // ---- PV ----
        __builtin_amdgcn_s_setprio(1);
        #pragma unroll
        for (int ks = 0; ks < 2; ++ks) {
            if (ks <= ksmax) {
                short8 pa = *(const short8*)&Plds[w][(qc * 64 + ks * 32 + g * 8) ^ pswz];
                #pragma unroll
                for (int db = 0; db < 8; ++db) {
                    const int d = db * 16 + qc;
                    short8 vf = *(const short8*)&Vlds[buf][(d * 64 + ks * 32 + g * 8) ^ ((d & 7) << 3)];
                    o[db] = __builtin_amdgcn_mfma_f32_16x16x32_bf16(pa, vf, o[db], 0, 0, 0);
                }
            }
        }
        __builtin_amdgcn_s_setprio(0);

        if (more) barrier();                // all waves done with buf before overwrite
    }

    // ---- epilogue ----
    lsum += __shfl_xor(lsum, 16);
    lsum += __shfl_xor(lsum, 32);

    if (MODE == 1 && pslot >= 0) {
        unsigned short* po = Po + (size_t)pslot * (QBLK * D_HEAD);
        #pragma unroll
        for (int db = 0; db < 8; ++db)
            #pragma unroll
            for (int r = 0; r < 4; ++r)
                po[(w * 16 + g * 4 + r) * D_HEAD + db * 16 + qc] = f2bf(o[db][r]);
        if (g == 0) {
            float* ml = Ml + (size_t)pslot * (QBLK * 2);
            ml[(w * 16 + qc) * 2 + 0] = m;
            ml[(w * 16 + qc) * 2 + 1] = lsum;
        }
    } else {
        float linv = 1.0f / lsum;
        float li[4];
        #pragma unroll
        for (int r = 0; r < 4; ++r) li[r] = __shfl(linv, g * 4 + r);
        #pragma unroll
        for (int db = 0; db < 8; ++db)
            #pragma unroll
            for (int r = 0; r < 4; ++r)
                Og[base + (size_t)(q0w + g * 4 + r) * D_HEAD + db * 16 + qc] = o[db][r] * li[r];
    }
}

// combine C in {2,3,4} chunks of each heavy q-block (qb 8..31)
__global__ __launch_bounds__(256)
void combine(const unsigned short* __restrict__ Po, const float* __restrict__ Ml,
             float* __restrict__ Og)
{
    const int z   = blockIdx.x;             // j*16 + b, j = qb-8 (keeps XCD=b%8)
    const int b   = z & 15;
    const int qb  = 8 + (z >> 4);
    const int tid = threadIdx.x;
    const int row = tid >> 2;
    const int c0  = (tid & 3) * 32;

    int C, o0;
    if (qb >= 24)      { C = 4; o0 = (31 - qb) * 4; }
    else if (qb >= 16) { C = 3; o0 = 32 + (23 - qb) * 3; }
    else               { C = 2; o0 = 56 + (15 - qb) * 2; }
    const int ps0 = b * PCH_PB + o0;

    float mm[4], ll[4];
    float M = -1e30f;
    for (int c = 0; c < C; ++c) {
        const float* ml = Ml + (size_t)(ps0 + c) * (QBLK * 2);
        mm[c] = ml[row * 2 + 0];
        ll[c] = ml[row * 2 + 1];
        M = fmaxf(M, mm[c]);
    }
    float denom = 0.f, wgt[4];
    for (int c = 0; c < C; ++c) {
        wgt[c] = exp2f(mm[c] - M);
        denom += wgt[c] * ll[c];
    }
    const float rd = 1.0f / denom;

    float acc[32];
    #pragma unroll
    for (int j = 0; j < 32; ++j) acc[j] = 0.f;
    for (int c = 0; c < C; ++c) {
        const unsigned short* po = Po + (size_t)(ps0 + c) * (QBLK * D_HEAD) + row * D_HEAD + c0;
        const float wc = wgt[c];
        #pragma unroll
        for (int j = 0; j < 4; ++j) {
            uint4 u = *(const uint4*)(po + j * 8);
            const unsigned short* h = (const unsigned short*)&u;
            #pragma unroll
            for (int e = 0; e < 8; ++e) acc[j * 8 + e] += wc * bf2f(h[e]);
        }
    }
    float* op = Og + (size_t)b * S_LEN * D_HEAD + (size_t)(qb * QBLK + row) * D_HEAD + c0;
    #pragma unroll
    for (int j = 0; j < 8; ++j) {
        float4 r = { acc[j*4+0] * rd, acc[j*4+1] * rd, acc[j*4+2] * rd, acc[j*4+3] * rd };
        *(float4*)(op + j * 4) = r;
    }
}

extern "C" void kernel_launch(void* const* d_in, const int* in_sizes, int n_in,
                              void* d_out, int out_size, void* d_ws, size_t ws_size,
                              hipStream_t stream) {
    const float* Q = (const float*)d_in[0];
    const float* K = (const float*)d_in[1];
    const float* V = (const float*)d_in[2];
    float* O = (float*)d_out;

    const size_t tile_elems = (size_t)BATCH * NKVT * TILE_SH;
    unsigned short* Kp = (unsigned short*)d_ws;
    unsigned short* Vp = Kp + tile_elems;
    unsigned short* Po = Vp + tile_elems;                       // 1152 * 8192 bf16
    float*          Mlp = (float*)(Po + (size_t)BATCH * PCH_PB * QBLK * D_HEAD);
    const size_t need_bytes = (char*)(Mlp + (size_t)BATCH * PCH_PB * QBLK * 2) - (char*)d_ws;

    prep<<<dim3(BATCH * NKVT), dim3(256), 0, stream>>>(K, V, Kp, Vp);
    if (ws_size >= need_bytes) {
        attn_fwd<1><<<dim3(CH_PB * BATCH), dim3(256), 0, stream>>>(Q, Kp, Vp, O, Po, Mlp);
        combine<<<dim3(24 * BATCH), dim3(256), 0, stream>>>(Po, Mlp, O);
    } else {
        attn_fwd<0><<<dim3(512), dim3(256), 0, stream>>>(Q, Kp, Vp, O, nullptr, nullptr);
    }
}

// Round 8
// 71.050 us; speedup vs baseline: 1.0708x; 1.0708x over previous
//
#include <hip/hip_runtime.h>
#include <math.h>

#define S_LEN  2048
#define D_HEAD 128
#define QBLK   64
#define KVBLK  64
#define NWAVES 4
#define BATCH  16
#define NKVT   (S_LEN / KVBLK)     // 32 kv tiles per batch
#define TILE_SH 8192               // shorts per 64x128 tile image (16 KB)

typedef __attribute__((ext_vector_type(4))) float f32x4;
typedef __attribute__((ext_vector_type(8))) short short8;

__device__ __forceinline__ unsigned short f2bf(float x) {
    union { float f; unsigned u; } v; v.f = x;
    unsigned r = v.u + 0x7fffu + ((v.u >> 16) & 1u);
    return (unsigned short)(r >> 16);
}
__device__ __forceinline__ float bf2f(unsigned short h) {
    union { unsigned u; float f; } v; v.u = ((unsigned)h) << 16;
    return v.f;
}
__device__ __forceinline__ unsigned pack2(unsigned short a, unsigned short b) {
    return (unsigned)a | ((unsigned)b << 16);
}
__device__ __forceinline__ unsigned cvtpk(float lo, float hi) {
    unsigned r;
    asm("v_cvt_pk_bf16_f32 %0, %1, %2" : "=v"(r) : "v"(lo), "v"(hi));
    return r;
}
__device__ __forceinline__ void gld16(const void* g, void* l) {
    __builtin_amdgcn_global_load_lds(
        (const __attribute__((address_space(1))) void*)g,
        (__attribute__((address_space(3))) void*)l, 16, 0, 0);
}
template<int N> __device__ __forceinline__ void wait_vm() {
    asm volatile("s_waitcnt vmcnt(%0)" :: "i"(N) : "memory");
}
__device__ __forceinline__ void barrier() {
    __builtin_amdgcn_sched_barrier(0);
    __builtin_amdgcn_s_barrier();
    __builtin_amdgcn_sched_barrier(0);
}

// prep: one block per (batch, kv-tile). Emits PRE-SWIZZLED contiguous LDS images.
__global__ __launch_bounds__(256) void prep(const float* __restrict__ K,
                                            const float* __restrict__ V,
                                            unsigned short* __restrict__ Kp,
                                            unsigned short* __restrict__ Vp)
{
    const int tid = threadIdx.x;
    const int bid = blockIdx.x;
    const int b = bid >> 5, t = bid & 31;
    const size_t ibase = (size_t)b * S_LEN * D_HEAD + (size_t)t * KVBLK * D_HEAD;
    unsigned short* ko = Kp + (size_t)bid * TILE_SH;
    unsigned short* vo = Vp + (size_t)bid * TILE_SH;

    #pragma unroll
    for (int c = 0; c < 4; ++c) {
        int i  = c * 256 + tid;
        int k  = i >> 4;
        int d8 = ((i & 15) * 8) ^ ((k & 7) << 3);
        const float* sp = K + ibase + (size_t)k * D_HEAD + d8;
        float4 a = *(const float4*)sp;
        float4 bb = *(const float4*)(sp + 4);
        uint4 u = { pack2(f2bf(a.x),f2bf(a.y)),  pack2(f2bf(a.z),f2bf(a.w)),
                    pack2(f2bf(bb.x),f2bf(bb.y)),pack2(f2bf(bb.z),f2bf(bb.w)) };
        *(uint4*)(ko + i * 8) = u;
    }

    __shared__ unsigned short Vb[KVBLK][D_HEAD + 2];
    {
        const int r  = tid >> 2;
        const int c0 = (tid & 3) * 32;
        const float* sp = V + ibase + (size_t)r * D_HEAD + c0;
        #pragma unroll
        for (int i = 0; i < 8; ++i) {
            float4 x = *(const float4*)(sp + i * 4);
            Vb[r][c0+i*4+0] = f2bf(x.x); Vb[r][c0+i*4+1] = f2bf(x.y);
            Vb[r][c0+i*4+2] = f2bf(x.z); Vb[r][c0+i*4+3] = f2bf(x.w);
        }
    }
    __syncthreads();
    #pragma unroll
    for (int c = 0; c < 4; ++c) {
        int i   = c * 256 + tid;
        int d   = i >> 3;
        int kk0 = ((i & 7) * 8) ^ ((d & 7) << 3);
        unsigned short h[8];
        #pragma unroll
        for (int j = 0; j < 8; ++j) h[j] = Vb[kk0 + j][d];
        uint4 u = { pack2(h[0],h[1]), pack2(h[2],h[3]), pack2(h[4],h[5]), pack2(h[6],h[7]) };
        *(uint4*)(vo + i * 8) = u;
    }
}

// MODE 1: 640 blocks, bid = o*16 + b (XCD = b%8; 2 batches/XCD).
//   o<8 : merged chain, qb=o then qb=15-o sequentially (17 tiles, direct O).
//   o>=8: heavy half, qb = 31-((o-8)>>1), half = (o-8)&1 (8..16 tiles, bf16 partial).
// MODE 0 (fallback): 512 blocks, complementary pairing, all direct.
template<int MODE>
__global__ __launch_bounds__(256, 4)
void attn_fwd(const float* __restrict__ Qg, const unsigned short* __restrict__ Kp,
              const unsigned short* __restrict__ Vp, float* __restrict__ Og,
              unsigned short* __restrict__ Po, float* __restrict__ Ml)
{
    constexpr float CSC = 0.12751744f;      // log2(e)/sqrt(128), folded into Q
    const int tid  = threadIdx.x;
    const int lane = tid & 63;
    const int w    = tid >> 6;
    const int bid  = blockIdx.x;

    int b, qb0, lo0, n0, qb1 = -1, n1 = 0, pslot = -1;
    if (MODE == 0) {
        b = bid & 15;
        const int rank = bid >> 4;
        qb0 = (rank < 16) ? (31 - rank) : (rank - 16);
        lo0 = 0; n0 = qb0 + 1;
    } else {
        const int o = bid >> 4;
        b = bid & 15;
        if (o < 8) {                        // merged: 17 tiles direct
            qb0 = o;      lo0 = 0; n0 = qb0 + 1;
            qb1 = 15 - o; n1 = qb1 + 1;     // 16 - o
        } else {                            // heavy half: partial
            const int t = o - 8;
            qb0 = 31 - (t >> 1);
            const int n = qb0 + 1, h = (n + 1) >> 1, half = t & 1;
            lo0 = half ? h : 0;
            n0  = half ? (n - h) : h;
            pslot = b * 32 + t;
        }
    }
    const int nt = n0 + n1;
    const int qc = lane & 15;
    const int g  = lane >> 4;

    __shared__ __align__(16) unsigned short Klds[TILE_SH];            // 16 KB
    __shared__ __align__(16) unsigned short Vlds[TILE_SH];            // 16 KB
    __shared__ __align__(16) unsigned short Plds[NWAVES][16 * KVBLK]; //  8 KB

    const size_t base = (size_t)b * S_LEN * D_HEAD;
    const int tb = b * NKVT;

    short8 qf[4];
    auto load_q = [&](int qbx) {            // Q fragments (MFMA B operand), scaled
        const int q0wx = qbx * QBLK + w * 16;
        const float* qp = Qg + base + (size_t)(q0wx + qc) * D_HEAD + g * 8;
        #pragma unroll
        for (int db = 0; db < 4; ++db) {
            float4 x0 = *(const float4*)(qp + db * 32);
            float4 x1 = *(const float4*)(qp + db * 32 + 4);
            float tt[8] = {x0.x, x0.y, x0.z, x0.w, x1.x, x1.y, x1.z, x1.w};
            short8 f;
            #pragma unroll
            for (int j = 0; j < 8; ++j) f[j] = (short)f2bf(tt[j] * CSC);
            qf[db] = f;
        }
    };

    auto stage_K = [&](int t) {             // 4 DMA issues/wave
        const unsigned short* ks = Kp + (size_t)(tb + t) * TILE_SH + w * 2048 + lane * 8;
        #pragma unroll
        for (int ii = 0; ii < 4; ++ii) gld16(ks + ii * 512, &Klds[w * 2048 + ii * 512]);
    };
    auto stage_V = [&](int t) {
        const unsigned short* vs = Vp + (size_t)(tb + t) * TILE_SH + w * 2048 + lane * 8;
        #pragma unroll
        for (int ii = 0; ii < 4; ++ii) gld16(vs + ii * 512, &Vlds[w * 2048 + ii * 512]);
    };

    f32x4 o[8] = {};                        // o[db][r] = O[q=4g+r][d=db*16+qc]
    float m = -1e30f, lsum = 0.f;           // lsum lane-partial until epilogue

    auto epi_direct = [&](int qbx) {        // normalize + write O for q-block qbx
        float ls = lsum;
        ls += __shfl_xor(ls, 16);
        ls += __shfl_xor(ls, 32);
        float linv = 1.0f / ls;
        float li[4];
        #pragma unroll
        for (int r = 0; r < 4; ++r) li[r] = __shfl(linv, g * 4 + r);
        const int q0wx = qbx * QBLK + w * 16;
        #pragma unroll
        for (int db = 0; db < 8; ++db)
            #pragma unroll
            for (int r = 0; r < 4; ++r)
                Og[base + (size_t)(q0wx + g * 4 + r) * D_HEAD + db * 16 + qc] = o[db][r] * li[r];
    };

    int qb_c = qb0;
    int q0w  = qb_c * QBLK + w * 16;
    int qidx = q0w + qc;

    load_q(qb_c);
    stage_K(lo0);
    stage_V(lo0);

    for (int u = 0; u < nt; ++u) {
        const int t    = (u < n0) ? (lo0 + u) : (u - n0);
        const int kv0  = t * KVBLK;
        const bool more = (u + 1 < nt);
        const int tnxt = more ? ((u + 1 < n0) ? (lo0 + u + 1) : (u + 1 - n0)) : 0;

        // K[t] landed in every wave before anyone reads it
        wait_vm<4>();
        barrier();

        const int t16max = min(3, (q0w + 15 - kv0) >> 4);
        const int ksmax  = min(1, (q0w + 15 - kv0) >> 5);

        // ---- swapped QK^T: rows = k, cols = q ----
        f32x4 st[4] = {};
        __builtin_amdgcn_s_setprio(1);
        #pragma unroll
        for (int t16 = 0; t16 < 4; ++t16) {
            if (t16 <= t16max) {
                const int kr = t16 * 16 + qc;
                const int swz = (kr & 7) << 3;
                #pragma unroll
                for (int db = 0; db < 4; ++db) {
                    short8 kf = *(const short8*)&Klds[(kr * 128 + db * 32 + g * 8) ^ swz];
                    st[t16] = __builtin_amdgcn_mfma_f32_16x16x32_bf16(kf, qf[db], st[t16], 0, 0, 0);
                }
            }
        }
        __builtin_amdgcn_s_setprio(0);

        barrier();                           // all waves done reading Klds
        if (more) stage_K(tnxt);             // K DMA hides under softmax + PV

        float s[16];
        #pragma unroll
        for (int t16 = 0; t16 < 4; ++t16)
            #pragma unroll
            for (int r = 0; r < 4; ++r)
                s[t16*4+r] = (t16 <= t16max) ? st[t16][r] : -1e30f;

        if (kv0 + KVBLK - 1 > q0w) {         // diagonal: per-lane causal mask
            #pragma unroll
            for (int t16 = 0; t16 < 4; ++t16)
                #pragma unroll
                for (int r = 0; r < 4; ++r)
                    if (kv0 + t16 * 16 + g * 4 + r > qidx) s[t16*4+r] = -1e30f;
        }

        // ---- online softmax, defer-max; no cross-lane ops in common path ----
        float m0 = fmaxf(fmaxf(s[0],s[1]), fmaxf(s[2],s[3]));
        float m1 = fmaxf(fmaxf(s[4],s[5]), fmaxf(s[6],s[7]));
        float m2 = fmaxf(fmaxf(s[8],s[9]), fmaxf(s[10],s[11]));
        float m3 = fmaxf(fmaxf(s[12],s[13]), fmaxf(s[14],s[15]));
        float mx = fmaxf(fmaxf(m0,m1), fmaxf(m2,m3));

        if (__any(mx > m + 8.0f)) {
            mx = fmaxf(mx, __shfl_xor(mx, 16));
            mx = fmaxf(mx, __shfl_xor(mx, 32));
            float mnew = fmaxf(m, mx);
            float alpha = exp2f(m - mnew);
            m = mnew;
            lsum *= alpha;
            float a_o[4];
            #pragma unroll
            for (int r = 0; r < 4; ++r) a_o[r] = __shfl(alpha, g * 4 + r);
            #pragma unroll
            for (int db = 0; db < 8; ++db)
                #pragma unroll
                for (int r = 0; r < 4; ++r) o[db][r] *= a_o[r];
        }

        float p[16];
        #pragma unroll
        for (int ii = 0; ii < 16; ++ii) p[ii] = exp2f(s[ii] - m);
        float r0 = (p[0]+p[1]) + (p[2]+p[3]);
        float r1 = (p[4]+p[5]) + (p[6]+p[7]);
        float r2 = (p[8]+p[9]) + (p[10]+p[11]);
        float r3 = (p[12]+p[13]) + (p[14]+p[15]);
        lsum += (r0+r1) + (r2+r3);

        // V[t] landed in every wave before anyone reads it
        if (more) wait_vm<4>(); else wait_vm<0>();
        barrier();

        // ---- P -> wave-private LDS (bf16, swizzled) ----
        const int pswz = (qc & 7) << 3;
        #pragma unroll
        for (int t16 = 0; t16 < 4; ++t16) {
            uint2 uu = { cvtpk(p[t16*4+0], p[t16*4+1]), cvtpk(p[t16*4+2], p[t16*4+3]) };
            *(uint2*)&Plds[w][(qc * 64 + t16 * 16 + g * 4) ^ pswz] = uu;
        }

        // ---- PV ----
        __builtin_amdgcn_s_setprio(1);
        #pragma unroll
        for (int ks = 0; ks < 2; ++ks) {
            if (ks <= ksmax) {
                short8 pa = *(const short8*)&Plds[w][(qc * 64 + ks * 32 + g * 8) ^ pswz];
                #pragma unroll
                for (int db = 0; db < 8; ++db) {
                    const int d = db * 16 + qc;
                    short8 vf = *(const short8*)&Vlds[(d * 64 + ks * 32 + g * 8) ^ ((d & 7) << 3)];
                    o[db] = __builtin_amdgcn_mfma_f32_16x16x32_bf16(pa, vf, o[db], 0, 0, 0);
                }
            }
        }
        __builtin_amdgcn_s_setprio(0);

        barrier();                           // all waves done reading Vlds
        if (more) stage_V(tnxt);             // V DMA hides under next QK^T

        // ---- segment boundary (merged chains): flush qb0, switch to qb1 ----
        if (MODE == 1 && n1 > 0 && u == n0 - 1) {
            epi_direct(qb_c);
            qb_c = qb1;
            q0w  = qb_c * QBLK + w * 16;
            qidx = q0w + qc;
            load_q(qb_c);
            #pragma unroll
            for (int db = 0; db < 8; ++db) o[db] = (f32x4){0.f, 0.f, 0.f, 0.f};
            m = -1e30f; lsum = 0.f;
        }
    }

    // ---- final epilogue ----
    if (MODE == 1 && pslot >= 0) {
        float ls = lsum;
        ls += __shfl_xor(ls, 16);
        ls += __shfl_xor(ls, 32);
        unsigned short* po = Po + (size_t)pslot * (QBLK * D_HEAD);
        #pragma unroll
        for (int db = 0; db < 8; ++db)
            #pragma unroll
            for (int r = 0; r < 4; ++r)
                po[(w * 16 + g * 4 + r) * D_HEAD + db * 16 + qc] = f2bf(o[db][r]);
        if (g == 0) {
            float* ml = Ml + (size_t)pslot * (QBLK * 2);
            ml[(w * 16 + qc) * 2 + 0] = m;
            ml[(w * 16 + qc) * 2 + 1] = ls;
        }
    } else {
        epi_direct(qb_c);
    }
}

// combine the two KV-halves of each heavy q-block (qb 16..31)
__global__ __launch_bounds__(256)
void combine(const unsigned short* __restrict__ Po, const float* __restrict__ Ml,
             float* __restrict__ Og)
{
    const int z   = blockIdx.x;             // (qb-16)*16 + b  (XCD = b%8)
    const int b   = z & 15;
    const int qb  = 16 + (z >> 4);
    const int tid = threadIdx.x;
    const int row = tid >> 2;
    const int c0  = (tid & 3) * 32;

    const int pA = b * 32 + 2 * (31 - qb);
    const int pB = pA + 1;

    const float* mlA = Ml + (size_t)pA * (QBLK * 2);
    const float* mlB = Ml + (size_t)pB * (QBLK * 2);
    const float mA = mlA[row*2], lA = mlA[row*2+1];
    const float mB = mlB[row*2], lB = mlB[row*2+1];
    const float M  = fmaxf(mA, mB);
    const float aA = exp2f(mA - M), aB = exp2f(mB - M);
    const float rd = 1.0f / (aA * lA + aB * lB);

    const unsigned short* poA = Po + (size_t)pA * (QBLK * D_HEAD) + row * D_HEAD + c0;
    const unsigned short* poB = Po + (size_t)pB * (QBLK * D_HEAD) + row * D_HEAD + c0;
    float* op = Og + (size_t)b * S_LEN * D_HEAD + (size_t)(qb * QBLK + row) * D_HEAD + c0;

    #pragma unroll
    for (int j = 0; j < 4; ++j) {
        uint4 ua = *(const uint4*)(poA + j * 8);
        uint4 ub = *(const uint4*)(poB + j * 8);
        const unsigned short* ha = (const unsigned short*)&ua;
        const unsigned short* hb = (const unsigned short*)&ub;
        float4 o0, o1;
        o0.x = (aA*bf2f(ha[0]) + aB*bf2f(hb[0])) * rd;
        o0.y = (aA*bf2f(ha[1]) + aB*bf2f(hb[1])) * rd;
        o0.z = (aA*bf2f(ha[2]) + aB*bf2f(hb[2])) * rd;
        o0.w = (aA*bf2f(ha[3]) + aB*bf2f(hb[3])) * rd;
        o1.x = (aA*bf2f(ha[4]) + aB*bf2f(hb[4])) * rd;
        o1.y = (aA*bf2f(ha[5]) + aB*bf2f(hb[5])) * rd;
        o1.z = (aA*bf2f(ha[6]) + aB*bf2f(hb[6])) * rd;
        o1.w = (aA*bf2f(ha[7]) + aB*bf2f(hb[7])) * rd;
        *(float4*)(op + j * 8)     = o0;
        *(float4*)(op + j * 8 + 4) = o1;
    }
}

extern "C" void kernel_launch(void* const* d_in, const int* in_sizes, int n_in,
                              void* d_out, int out_size, void* d_ws, size_t ws_size,
                              hipStream_t stream) {
    const float* Q = (const float*)d_in[0];
    const float* K = (const float*)d_in[1];
    const float* V = (const float*)d_in[2];
    float* O = (float*)d_out;

    const size_t tile_elems = (size_t)BATCH * NKVT * TILE_SH;
    unsigned short* Kp = (unsigned short*)d_ws;
    unsigned short* Vp = Kp + tile_elems;
    unsigned short* Po = Vp + tile_elems;                       // 512 * 8192 bf16
    float*          Mlp = (float*)(Po + (size_t)512 * QBLK * D_HEAD);
    const size_t need_bytes = (char*)(Mlp + (size_t)512 * QBLK * 2) - (char*)d_ws;

    prep<<<dim3(BATCH * NKVT), dim3(256), 0, stream>>>(K, V, Kp, Vp);
    if (ws_size >= need_bytes) {
        attn_fwd<1><<<dim3(640), dim3(256), 0, stream>>>(Q, Kp, Vp, O, Po, Mlp);
        combine<<<dim3(256), dim3(256), 0, stream>>>(Po, Mlp, O);
    } else {
        attn_fwd<0><<<dim3(512), dim3(256), 0, stream>>>(Q, Kp, Vp, O, nullptr, nullptr);
    }
}